// Round 7
// baseline (214.559 us; speedup 1.0000x reference)
//
#include <hip/hip_runtime.h>
#include <stdint.h>

// out[b,n] = sum_{c,hw} x[b,c,hw]*W_s[n,hw]*W_d[n,c] + W_b[n]
// GEMM: A = x (M=8192, K=3136), B = W_s (N=1024, K=3136), fused c-contraction.
// R6: LDS-pipe roofline attack. Wave tile 128x64 (8x4 frags) -> 12 ds_read_b128
//     per 32 MFMA (was 8 per 16): FLOP/LDS-byte 32 -> 42.7. Block = 4 waves,
//     tile 256x128, BK=64, 48 KB LDS, split-K x3 (grid 768 = 3 blocks/CU,
//     12 waves/CU, launch_bounds(256,3) -> <=170 VGPR for acc[8][4]=128).

#define K_DIM 3136
#define N_DIM 1024
#define C_DIM 256
#define B_DIM 32
#define M_DIM 8192
#define X_ELEMS (M_DIM * K_DIM)   // 25690112
#define WS_ELEMS (N_DIM * K_DIM)  // 3211264

typedef __attribute__((ext_vector_type(8))) short short8v;  // 8 bf16
typedef __attribute__((ext_vector_type(4))) float f32x4;

__device__ __forceinline__ short f2bf(float f) {
  union { float f; unsigned u; } v; v.f = f;
  unsigned r = v.u + 0x7FFFu + ((v.u >> 16) & 1u);
  return (short)(r >> 16);
}

// 16B-per-lane async global->LDS. LDS dest = wave-uniform base + lane*16.
__device__ __forceinline__ void async16(const void* g, void* l) {
  __builtin_amdgcn_global_load_lds(
      (const __attribute__((address_space(1))) unsigned int*)g,
      (__attribute__((address_space(3))) unsigned int*)l, 16, 0, 0);
}

// fp32 -> bf16 for x and W_s, plus bias broadcast into out (last 128 blocks).
#define XBLK (X_ELEMS / 2048)                 // 12544
#define CVBLK ((X_ELEMS + WS_ELEMS) / 2048)   // 14112
__global__ __launch_bounds__(256) void convert_bf16_bias(
    const float* __restrict__ x, const float* __restrict__ Ws,
    const float* __restrict__ Wb, short* __restrict__ dst,
    float* __restrict__ out) {
  int bid = blockIdx.x;
  if (bid >= CVBLK) {  // bias: 32768 out elems / 256 = 128 blocks
    int i = (bid - CVBLK) * 256 + threadIdx.x;
    out[i] = Wb[i & (N_DIM - 1)];
    return;
  }
  const float* src;
  short* d;
  size_t base;
  if (bid < XBLK) {
    src = x; d = dst; base = (size_t)bid * 2048;
  } else {
    src = Ws; d = dst + X_ELEMS; base = (size_t)(bid - XBLK) * 2048;
  }
  size_t i = base + threadIdx.x * 8;
  f32x4 v0 = __builtin_nontemporal_load((const f32x4*)(src + i));
  f32x4 v1 = __builtin_nontemporal_load((const f32x4*)(src + i) + 1);
  short8v s;
  s[0] = f2bf(v0.x); s[1] = f2bf(v0.y); s[2] = f2bf(v0.z); s[3] = f2bf(v0.w);
  s[4] = f2bf(v1.x); s[5] = f2bf(v1.y); s[6] = f2bf(v1.z); s[7] = f2bf(v1.w);
  *(short8v*)(d + i) = s;
}

// LDS: rows of 8 chunks (chunk = 8 bf16 = 16 B), unpadded (DMA dest).
// slot(row, cs) holds global chunk k8 = cs ^ (row&7); frag reads XOR back ->
// conflict-free (verified R1/R3: SQ_LDS_BANK_CONFLICT = 0).
__global__ __launch_bounds__(256, 3) void gemm_fused(
    const short* __restrict__ Abf, const short* __restrict__ Bbf,
    const float* __restrict__ Wd, float* __restrict__ out) {
  __shared__ __align__(16) short As[256 * 64];  // 32 KB
  __shared__ __align__(16) short Bs[128 * 64];  // 16 KB

  const int bid = blockIdx.x;
  const int mt = bid & 31;          // bid%8 == mt%8 -> A-tile pinned to XCD
  const int nt = (bid >> 5) & 7;
  const int z = bid >> 8;           // K-split third: 49 = 17 + 16 + 16
  const int kt0 = (z == 0) ? 0 : (17 + (z - 1) * 16);
  const int ktn = (z == 0) ? 17 : 16;

  const int t = threadIdx.x;
  const int lane = t & 63;
  const int wv = t >> 6;            // 0..3
  const int r = lane & 15;
  const int q = lane >> 4;
  const int wm = wv >> 1, wn = wv & 1;  // 2x2 wave grid; wave tile 128x64

  // staging: lane -> (rr, cs); each async16 instr = 8 rows x 8 chunks = 1 KB.
  // A: wave covers rows [wv*64, +64) via p=0..7; B: rows [wv*32, +32), p=0..3.
  const int rr = lane >> 3;
  const int k8 = (lane & 7) ^ rr;   // swizzled global chunk for this slot
  const short* Aw = Abf + (size_t)(mt * 256 + wv * 64 + rr) * K_DIM + k8 * 8 + kt0 * 64;
  const short* Bw = Bbf + (size_t)(nt * 128 + wv * 32 + rr) * K_DIM + k8 * 8 + kt0 * 64;
  char* AsB = (char*)As + wv * 8192;
  char* BsB = (char*)Bs + wv * 4096;

  f32x4 acc[8][4];
#pragma unroll
  for (int i = 0; i < 8; ++i)
#pragma unroll
    for (int j = 0; j < 4; ++j) acc[i][j] = (f32x4)0.0f;

  for (int kt = 0; kt < ktn; ++kt) {
    __syncthreads();  // prev iteration's LDS reads done
#pragma unroll
    for (int p = 0; p < 8; ++p)
      async16(Aw + (size_t)p * 8 * K_DIM + kt * 64, AsB + p * 1024);
#pragma unroll
    for (int p = 0; p < 4; ++p)
      async16(Bw + (size_t)p * 8 * K_DIM + kt * 64, BsB + p * 1024);
    __syncthreads();  // vmcnt(0) drain: DMA complete across all waves

#pragma unroll
    for (int ks = 0; ks < 2; ++ks) {
      const int xo = ((ks * 4 + q) ^ (r & 7)) * 16;
      short8v b[4];
#pragma unroll
      for (int j = 0; j < 4; ++j)
        b[j] = *(const short8v*)((const char*)Bs + (64 * wn + 16 * j + r) * 128 + xo);
#pragma unroll
      for (int i = 0; i < 8; ++i) {
        short8v a =
            *(const short8v*)((const char*)As + (128 * wm + 16 * i + r) * 128 + xo);
#pragma unroll
        for (int j = 0; j < 4; ++j)
          acc[i][j] = __builtin_amdgcn_mfma_f32_16x16x32_bf16(a, b[j],
                                                              acc[i][j], 0, 0, 0);
      }
    }
  }

  // epilogue: out[mt, n] += sum_c acc * W_d[n, c]; A-tile = image mt, c = row.
  // C/D frag layout: col = lane&15 (n), row = q*4 + reg (c).
#pragma unroll
  for (int j = 0; j < 4; ++j) {
    const int n_g = nt * 128 + 64 * wn + 16 * j + r;
    float p = 0.0f;
#pragma unroll
    for (int i = 0; i < 8; ++i) {
      const int c_l = 128 * wm + 16 * i + 4 * q;
      const float4 wd = *(const float4*)(Wd + (size_t)n_g * C_DIM + c_l);
      p += acc[i][j].x * wd.x + acc[i][j].y * wd.y + acc[i][j].z * wd.z +
           acc[i][j].w * wd.w;
    }
    p += __shfl_xor(p, 16, 64);
    p += __shfl_xor(p, 32, 64);
    if (q == 0) atomicAdd(&out[(size_t)mt * N_DIM + n_g], p);
  }
}

extern "C" void kernel_launch(void* const* d_in, const int* in_sizes, int n_in,
                              void* d_out, int out_size, void* d_ws, size_t ws_size,
                              hipStream_t stream) {
  const float* x = (const float*)d_in[0];
  const float* Ws = (const float*)d_in[1];
  const float* Wd = (const float*)d_in[2];
  const float* Wb = (const float*)d_in[3];
  float* out = (float*)d_out;
  short* xbf = (short*)d_ws;  // [X_ELEMS] bf16 x, then [WS_ELEMS] bf16 W_s

  convert_bf16_bias<<<dim3(CVBLK + 128), dim3(256), 0, stream>>>(x, Ws, Wb, xbf, out);
  gemm_fused<<<dim3(32 * 8 * 3), dim3(256), 0, stream>>>(xbf, xbf + X_ELEMS, Wd, out);
}